// Round 8
// baseline (2307.522 us; speedup 1.0000x reference)
//
#include <hip/hip_runtime.h>
#include <cstdint>
#include <cstddef>

#define Tn 2048
#define Bn 2
#define Hn 12
#define Cn 768
#define Ln 4
#define Vn 50257

typedef unsigned short ushort_t;
typedef __attribute__((ext_vector_type(8))) __bf16 bf16x8;
typedef __attribute__((ext_vector_type(8))) unsigned short u16x8;
typedef __attribute__((ext_vector_type(4))) float f32x4;

static constexpr size_t QKV_ELEMS = (size_t)Bn * Hn * Tn * 64;  // 3,145,728

__device__ inline unsigned short f2bf(float f) {
  unsigned int u = __float_as_uint(f);
  unsigned int r = (u + 0x7fffu + ((u >> 16) & 1u)) >> 16;
  return (unsigned short)r;
}

__device__ inline f32x4 zero4() { f32x4 z; z[0]=0.f; z[1]=0.f; z[2]=0.f; z[3]=0.f; return z; }

__device__ inline void gload_lds16(const ushort_t* g, ushort_t* l) {
  __builtin_amdgcn_global_load_lds(
      (const __attribute__((address_space(1))) void*)g,
      (__attribute__((address_space(3))) void*)l, 16, 0, 0);
}

// bijective XCD-chunked swizzle (m204)
__device__ inline int swz_lin() {
  int nbm = gridDim.x;
  int lin = blockIdx.y * nbm + blockIdx.x;
  int nwg = nbm * gridDim.y;
  int q = nwg >> 3, r = nwg & 7, x = lin & 7, p = lin >> 3;
  return (x < r ? x * (q + 1) : r * (q + 1) + (x - r) * q) + p;
}

// ---------------- embedding ----------------
__global__ __launch_bounds__(256) void embed_kernel(const int* __restrict__ idx,
    const float* __restrict__ tok, const float* __restrict__ pos, float* __restrict__ x) {
  int row = blockIdx.x;
  int t = row & (Tn - 1);
  int token = idx[row];
  const float* tr = tok + (size_t)token * Cn;
  const float* pr = pos + (size_t)t * Cn;
  float* xr = x + (size_t)row * Cn;
  for (int c = threadIdx.x; c < Cn; c += 256) xr[c] = tr[c] + pr[c];
}

// ---------------- layernorm -> bf16 ----------------
__global__ __launch_bounds__(256) void ln_kernel(const float* __restrict__ x,
    const float* __restrict__ gam, const float* __restrict__ bet, ushort_t* __restrict__ out) {
  int row = blockIdx.x;
  const float* xr = x + (size_t)row * Cn;
  float v[3]; float s = 0.f, s2 = 0.f;
  #pragma unroll
  for (int e = 0; e < 3; ++e) { float t = xr[threadIdx.x + e*256]; v[e] = t; s += t; s2 += t*t; }
  #pragma unroll
  for (int off = 32; off >= 1; off >>= 1) { s += __shfl_xor(s, off); s2 += __shfl_xor(s2, off); }
  __shared__ float red[8];
  int w = threadIdx.x >> 6;
  if ((threadIdx.x & 63) == 0) { red[w] = s; red[4 + w] = s2; }
  __syncthreads();
  s  = red[0] + red[1] + red[2] + red[3];
  s2 = red[4] + red[5] + red[6] + red[7];
  float mean = s * (1.f / Cn);
  float var  = s2 * (1.f / Cn) - mean * mean;
  float rstd = rsqrtf(var + 1e-5f);
  ushort_t* orow = out + (size_t)row * Cn;
  #pragma unroll
  for (int e = 0; e < 3; ++e) {
    int c = threadIdx.x + e*256;
    orow[c] = f2bf((v[e] - mean) * rstd * gam[c] + bet[c]);
  }
}

// ---------------- transpose + f32->bf16 weight conversion ----------------
__global__ __launch_bounds__(256) void tcvt_kernel(const float* __restrict__ in,
    ushort_t* __restrict__ out, int K, int N, int Npad) {
  __shared__ float tile[32][33];
  int n0 = blockIdx.x * 32, k0 = blockIdx.y * 32;
  int tx = threadIdx.x, ty = threadIdx.y;
  #pragma unroll
  for (int r = 0; r < 4; ++r) {
    int k = k0 + ty + 8*r;
    int n = n0 + tx;
    tile[ty + 8*r][tx] = (n < N) ? in[(size_t)k * N + n] : 0.f;
  }
  __syncthreads();
  #pragma unroll
  for (int r = 0; r < 4; ++r) {
    int n = n0 + ty + 8*r;
    out[(size_t)n * K + k0 + tx] = f2bf(tile[tx][ty + 8*r]);
  }
}

// ---------------- bf16 64x64 tile transpose: [BH,T,64] -> [BH,64,T] ----------------
__global__ __launch_bounds__(256) void vtrans_kernel(const ushort_t* __restrict__ vin,
                                                     ushort_t* __restrict__ vout) {
  __shared__ ushort_t tile[64][65];
  int t0 = blockIdx.x * 64;
  size_t bh = blockIdx.y;
  const ushort_t* src = vin + (bh * Tn + t0) * 64;
  int row = threadIdx.x >> 2, c0 = (threadIdx.x & 3) * 16;
  u16x8 a = *(const u16x8*)&src[(size_t)row * 64 + c0];
  u16x8 b = *(const u16x8*)&src[(size_t)row * 64 + c0 + 8];
  #pragma unroll
  for (int j = 0; j < 8; ++j) { tile[row][c0 + j] = a[j]; tile[row][c0 + 8 + j] = b[j]; }
  __syncthreads();
  int d = threadIdx.x >> 2, tq = (threadIdx.x & 3) * 16;
  u16x8 o0, o1;
  #pragma unroll
  for (int j = 0; j < 8; ++j) { o0[j] = tile[tq + j][d]; o1[j] = tile[tq + 8 + j][d]; }
  ushort_t* dst = vout + (bh * 64 + d) * Tn + t0 + tq;
  *(u16x8*)&dst[0] = o0;
  *(u16x8*)&dst[8] = o1;
}

// ======== 256x256 8-wave head GEMM: 3-buf LDS ring + T2 swizzle + NT stores ========
// C(MxN) f32 = A(MxK) * Bt^T (+bias); Bt (Npad x K) rows >= N zero-padded.
__global__ __launch_bounds__(512, 2) void gemm256_kernel(
    const ushort_t* __restrict__ A, const ushort_t* __restrict__ Bt,
    const float* __restrict__ bias, float* __restrict__ outp,
    int M, int N, int K) {
  __shared__ ushort_t lds[3 * 16384];   // 3 bufs x (A 16KB + B 16KB) = 96 KiB
  const int t = threadIdx.x;
  const int w = t >> 6, l = t & 63, lo = l & 15, g = l >> 4;
  const int wm = w >> 2, wn = w & 3;

  int bm, bn;
  {
    int seq = swz_lin();
    int gsz = 8 * gridDim.y;      // G=8 bm fast within supergroup; gridDim.x % 8 == 0
    int grp = seq / gsz;
    int t2 = seq - grp * gsz;
    bn = t2 >> 3;
    bm = grp * 8 + (t2 & 7);
  }

  const ushort_t* gAb = A  + (size_t)bm * 256 * K;
  const ushort_t* gBb = Bt + (size_t)bn * 256 * K;

  f32x4 acc[8][4];
  #pragma unroll
  for (int i = 0; i < 8; ++i)
    #pragma unroll
    for (int j = 0; j < 4; ++j) acc[i][j] = zero4();

  // stage tile kt into buf. LDS linear granule q=j*512+t -> row r=q>>2;
  // source col-granule = (q&3) ^ ((r>>1)&3)  [T2 inverse-swizzled SOURCE, rule #21]
  auto stage = [&](int kt, int buf) {
    const int k0 = kt << 5;
    #pragma unroll
    for (int j = 0; j < 2; ++j) {
      const int q = j * 512 + t;
      const int r = q >> 2;
      const int cc = ((q & 3) ^ ((r >> 1) & 3)) << 3;
      gload_lds16(gAb + (size_t)r * K + k0 + cc,
                  &lds[buf * 16384 + j * 4096 + w * 512]);
      gload_lds16(gBb + (size_t)r * K + k0 + cc,
                  &lds[buf * 16384 + 8192 + j * 4096 + w * 512]);
    }
  };
  const int csw = ((lo >> 1) & 3) << 3;   // read-side XOR, same involution
  auto compute = [&](int buf) {
    const ushort_t* as = &lds[buf * 16384];
    const ushort_t* bs = &lds[buf * 16384 + 8192];
    bf16x8 af[8], bfr[4];
    #pragma unroll
    for (int mi = 0; mi < 8; ++mi)
      af[mi] = *(const bf16x8*)&as[(wm*128 + mi*16 + lo) * 32 + ((g*8) ^ csw)];
    #pragma unroll
    for (int ni = 0; ni < 4; ++ni)
      bfr[ni] = *(const bf16x8*)&bs[(wn*64 + ni*16 + lo) * 32 + ((g*8) ^ csw)];
    __builtin_amdgcn_s_setprio(1);
    #pragma unroll
    for (int mi = 0; mi < 8; ++mi)
      #pragma unroll
      for (int ni = 0; ni < 4; ++ni)
        acc[mi][ni] = __builtin_amdgcn_mfma_f32_16x16x32_bf16(af[mi], bfr[ni], acc[mi][ni], 0, 0, 0);
    __builtin_amdgcn_s_setprio(0);
  };

  const int NK = K >> 5;
  stage(0, 0); stage(1, 1); stage(2, 2);
  asm volatile("s_waitcnt vmcnt(8)" ::: "memory");
  __builtin_amdgcn_s_barrier();

  int buf = 0;
  #pragma unroll 1
  for (int kt = 0; kt < NK; ++kt) {
    compute(buf);
    asm volatile("s_waitcnt lgkmcnt(0)" ::: "memory");
    __builtin_amdgcn_s_barrier();
    if (kt + 3 < NK) {
      stage(kt + 3, buf);
      asm volatile("s_waitcnt vmcnt(8)" ::: "memory");
    } else if (kt + 2 < NK) {
      asm volatile("s_waitcnt vmcnt(4)" ::: "memory");
    } else {
      asm volatile("s_waitcnt vmcnt(0)" ::: "memory");
    }
    __builtin_amdgcn_s_barrier();
    buf = (buf == 2) ? 0 : buf + 1;
  }

  #pragma unroll
  for (int mi = 0; mi < 8; ++mi) {
    #pragma unroll
    for (int ni = 0; ni < 4; ++ni) {
      int colg = bn*256 + wn*64 + ni*16 + lo;
      if (colg < N) {
        float bv = bias ? bias[colg] : 0.f;
        #pragma unroll
        for (int i = 0; i < 4; ++i) {
          int rowg = bm*256 + wm*128 + mi*16 + 4*g + i;
          __builtin_nontemporal_store(acc[mi][ni][i] + bv, &outp[(size_t)rowg * N + colg]);
        }
      }
    }
  }
}

// ---------------- GEMM (m97-style, 2-phase): C = A * Bt^T ----------------
// MODE 0: f32 = acc+bias ; 1: f32 = res+acc+bias ; 2: bf16 = gelu(acc+bias)
// MODE 3: q [B,H,T,64] (x0.125), k [B,H,T,64], v [B,H,T,64] (coalesced; vtrans later)
template<int MODE, int TM>
__global__ __launch_bounds__(256) void gemm_kernel(
    const ushort_t* __restrict__ A, const ushort_t* __restrict__ Bt,
    const float* __restrict__ bias, void* __restrict__ outp,
    const float* __restrict__ res, int M, int N, int K) {
  constexpr int MI = TM / 32;
  constexpr int ABUF = TM * 32;
  __shared__ ushort_t As[2 * ABUF];
  __shared__ ushort_t Bs[2 * 4096];
  const int t = threadIdx.x;
  int bm, bn;
  {
    int seq = swz_lin();
    const int G = 8;
    int NBN = gridDim.y;
    int gsz = G * NBN;
    int grp = seq / gsz;
    int t2 = seq - grp * gsz;
    bn = t2 / G;
    bm = grp * G + (t2 - bn * G);
  }
  const int w = t >> 6, l = t & 63, lo = l & 15, g = l >> 4;
  const int wm = w >> 1, wn = w & 1;

  f32x4 acc[MI][4];
  #pragma unroll
  for (int i = 0; i < MI; ++i)
    #pragma unroll
    for (int j = 0; j < 4; ++j) acc[i][j] = zero4();

  const int srow = t >> 2;
  const int scol = (t & 3) * 8;
  const ushort_t* gA = A  + (size_t)(bm * TM  + srow) * K + scol;
  const ushort_t* gB = Bt + (size_t)(bn * 128 + srow) * K + scol;
  ushort_t* lA = As + w * 512;
  ushort_t* lB = Bs + w * 512;

  auto stage = [&](int buf, int k0) {
    gload_lds16(gA + k0, lA + buf * ABUF);
    if (TM == 128) gload_lds16(gA + (size_t)64 * K + k0, lA + buf * ABUF + 2048);
    gload_lds16(gB + k0, lB + buf * 4096);
    gload_lds16(gB + (size_t)64 * K + k0, lB + buf * 4096 + 2048);
  };
  auto compute = [&](int buf) {
    const ushort_t* as = As + buf * ABUF;
    const ushort_t* bs = Bs + buf * 4096;
    bf16x8 af[MI], bfr[4];
    #pragma unroll
    for (int mi = 0; mi < MI; ++mi)
      af[mi] = *(const bf16x8*)&as[(size_t)(wm*(TM/2) + mi*16 + lo) * 32 + g*8];
    #pragma unroll
    for (int ni = 0; ni < 4; ++ni)
      bfr[ni] = *(const bf16x8*)&bs[(size_t)(wn*64 + ni*16 + lo) * 32 + g*8];
    #pragma unroll
    for (int mi = 0; mi < MI; ++mi)
      #pragma unroll
      for (int ni = 0; ni < 4; ++ni)
        acc[mi][ni] = __builtin_amdgcn_mfma_f32_16x16x32_bf16(af[mi], bfr[ni], acc[mi][ni], 0, 0, 0);
  };

  const int NK = K >> 5;
  stage(0, 0);
  __syncthreads();
  for (int kk = 0; kk < NK - 1; ++kk) {
    stage((kk + 1) & 1, (kk + 1) << 5);
    compute(kk & 1);
    __syncthreads();
  }
  compute((NK - 1) & 1);

  #pragma unroll
  for (int mi = 0; mi < MI; ++mi) {
    #pragma unroll
    for (int ni = 0; ni < 4; ++ni) {
      int colg = bn*128 + wn*64 + ni*16 + lo;
      if (colg < N) {
        float bv = bias ? bias[colg] : 0.f;
        #pragma unroll
        for (int i = 0; i < 4; ++i) {
          int rowg = bm*TM + wm*(TM/2) + mi*16 + 4*g + i;
          float vv = acc[mi][ni][i] + bv;
          if (MODE == 0) {
            ((float*)outp)[(size_t)rowg * N + colg] = vv;
          } else if (MODE == 1) {
            size_t off = (size_t)rowg * N + colg;
            ((float*)outp)[off] = res[off] + vv;
          } else if (MODE == 2) {
            float ge = 0.5f * vv * (1.f + erff(vv * 0.70710678118f));
            ((ushort_t*)outp)[(size_t)rowg * N + colg] = f2bf(ge);
          } else {
            int which = colg / Cn;
            int rem = colg - which * Cn;
            int h = rem >> 6, d = rem & 63;
            int b = rowg >> 11, tt = rowg & (Tn - 1);
            ushort_t* qb = (ushort_t*)outp;
            size_t bh = (size_t)(b * Hn + h);
            size_t off = (bh * Tn + tt) * 64 + d;
            if (which == 0)      qb[off] = f2bf(vv * 0.125f);
            else if (which == 1) qb[QKV_ELEMS + off] = f2bf(vv);
            else                 qb[3*QKV_ELEMS + off] = f2bf(vv);   // staging; vtrans -> 2*QKV
          }
        }
      }
    }
  }
}

// ---------------- flash attention (causal), 1 wave / 16 q-rows, no LDS ----------------
// + T12 cvt_pk pack, + T13 defer-max (wave-uniform skip)
__global__ __launch_bounds__(64) void attn_kernel(const ushort_t* __restrict__ qkvh,
                                                  ushort_t* __restrict__ y) {
  const int l = threadIdx.x;
  const int lo = l & 15, g = l >> 4;
  int nl = swz_lin();
  const int qt = nl & 127;
  const int bh = nl >> 7;
  const int b = bh / Hn, h = bh % Hn;
  const int q0 = qt * 16;
  const ushort_t* Qp = qkvh + (size_t)bh * Tn * 64;
  const ushort_t* Kp = qkvh + QKV_ELEMS + (size_t)bh * Tn * 64;
  const ushort_t* Vt = qkvh + 2*QKV_ELEMS + (size_t)bh * 64 * Tn;

  bf16x8 qf[2];
  #pragma unroll
  for (int ch = 0; ch < 2; ++ch)
    qf[ch] = *(const bf16x8*)&Qp[(size_t)(q0 + lo) * 64 + ch*32 + g*8];

  f32x4 of[4];
  #pragma unroll
  for (int ch = 0; ch < 4; ++ch) of[ch] = zero4();
  float m = -1e30f, lsum = 0.f;
  const int nkv = q0 + 16;
  const bool ghi = (g >= 2);
  const int lg2 = (g & 1) * 32;

  for (int kv0 = 0; kv0 < nkv; kv0 += 32) {
    bf16x8 vf[4];
    #pragma unroll
    for (int ch = 0; ch < 4; ++ch)
      vf[ch] = *(const bf16x8*)&Vt[(size_t)(ch*16 + lo) * Tn + kv0 + g*8];

    float s8[8];
    #pragma unroll
    for (int sub = 0; sub < 2; ++sub) {
      int kvb = kv0 + 16*sub;
      bf16x8 kf[2];
      #pragma unroll
      for (int ch = 0; ch < 2; ++ch)
        kf[ch] = *(const bf16x8*)&Kp[(size_t)(kvb + lo) * 64 + ch*32 + g*8];
      f32x4 st = zero4();
      st = __builtin_amdgcn_mfma_f32_16x16x32_bf16(kf[0], qf[0], st, 0, 0, 0);
      st = __builtin_amdgcn_mfma_f32_16x16x32_bf16(kf[1], qf[1], st, 0, 0, 0);
      #pragma unroll
      for (int i = 0; i < 4; ++i) {
        int kvi = kvb + 4*g + i;
        s8[sub*4 + i] = (kvi <= q0 + lo) ? st[i] : -1e30f;
      }
    }
    float tmax = s8[0];
    #pragma unroll
    for (int j = 1; j < 8; ++j) tmax = fmaxf(tmax, s8[j]);
    tmax = fmaxf(tmax, __shfl_xor(tmax, 16));
    tmax = fmaxf(tmax, __shfl_xor(tmax, 32));
    // T13 defer-max: if no row's max grew, skip rescale entirely (P = exp(s-m) <= 1)
    if (!__all(tmax <= m)) {
      float newm = fmaxf(m, tmax);
      float resc = __expf(m - newm);
      lsum *= resc;
      m = newm;
      #pragma unroll
      for (int i = 0; i < 4; ++i) {
        float rs = __shfl(resc, 4*g + i);
        of[0][i] *= rs; of[1][i] *= rs; of[2][i] *= rs; of[3][i] *= rs;
      }
    }
    float p8[8]; float psum = 0.f;
    #pragma unroll
    for (int j = 0; j < 8; ++j) { p8[j] = __expf(s8[j] - m); psum += p8[j]; }
    psum += __shfl_xor(psum, 16);
    psum += __shfl_xor(psum, 32);
    lsum += psum;
    // T12: pack P to bf16 pairs with v_cvt_pk_bf16_f32 (dst.lo=cvt(S0), dst.hi=cvt(S1))
    unsigned int q4[4];
    #pragma unroll
    for (int c = 0; c < 4; ++c)
      asm("v_cvt_pk_bf16_f32 %0, %1, %2" : "=v"(q4[c]) : "v"(p8[2*c]), "v"(p8[2*c+1]));
    union { unsigned int wv[4]; bf16x8 v; } pu;
    #pragma unroll
    for (int j = 0; j < 4; ++j) {
      int srcLane = lo + lg2 + ((j >> 1) << 4);
      unsigned int lo_w = (unsigned int)__shfl((int)q4[j & 1], srcLane);
      unsigned int hi_w = (unsigned int)__shfl((int)q4[2 + (j & 1)], srcLane);
      pu.wv[j] = ghi ? hi_w : lo_w;
    }
    #pragma unroll
    for (int ch = 0; ch < 4; ++ch)
      of[ch] = __builtin_amdgcn_mfma_f32_16x16x32_bf16(pu.v, vf[ch], of[ch], 0, 0, 0);
  }

  #pragma unroll
  for (int i = 0; i < 4; ++i) {
    float li = 1.f / __shfl(lsum, 4*g + i);
    of[0][i] *= li; of[1][i] *= li; of[2][i] *= li; of[3][i] *= li;
  }
  ushort_t* yb = y + ((size_t)b*Tn + q0) * Cn + h*64;
  #pragma unroll
  for (int ch = 0; ch < 4; ++ch)
    #pragma unroll
    for (int i = 0; i < 4; ++i)
      yb[(size_t)(4*g + i) * Cn + ch*16 + lo] = f2bf(of[ch][i]);
}

// ---------------- launch ----------------
extern "C" void kernel_launch(void* const* d_in, const int* in_sizes, int n_in,
                              void* d_out, int out_size, void* d_ws, size_t ws_size,
                              hipStream_t stream) {
  const int*   idx     = (const int*)d_in[0];
  const float* tok_emb = (const float*)d_in[1];
  const float* pos_emb = (const float*)d_in[2];
  const float* ln1_g   = (const float*)d_in[3];
  const float* ln1_b   = (const float*)d_in[4];
  const float* qkv_w   = (const float*)d_in[5];
  const float* qkv_b   = (const float*)d_in[6];
  const float* aproj_w = (const float*)d_in[7];
  const float* aproj_b = (const float*)d_in[8];
  const float* ln2_g   = (const float*)d_in[9];
  const float* ln2_b   = (const float*)d_in[10];
  const float* fc_w    = (const float*)d_in[11];
  const float* fc_b    = (const float*)d_in[12];
  const float* mproj_w = (const float*)d_in[13];
  const float* mproj_b = (const float*)d_in[14];
  const float* lnf_g   = (const float*)d_in[15];
  const float* lnf_b   = (const float*)d_in[16];
  const float* head_w  = (const float*)d_in[17];
  float* out = (float*)d_out;

  char* ws = (char*)d_ws;
  float*    x    = (float*)(ws);                         // 12,582,912 B
  ushort_t* hA   = (ushort_t*)(ws + 12582912);           //  6,291,456 B
  ushort_t* hB   = (ushort_t*)(ws + 18874368);           // 25,165,824 B
  ushort_t* qkvh = (ushort_t*)(ws + 44040192);           // 25,165,824 B (q,k,vT,vtmp)
  ushort_t* wT   = (ushort_t*)(ws + 69206016);           // 77,463,552 B (Npad 50432)

  const int M = Bn * Tn;  // 4096
  dim3 tb(32, 8);

  embed_kernel<<<M, 256, 0, stream>>>(idx, tok_emb, pos_emb, x);
  for (int l = 0; l < Ln; ++l) {
    ln_kernel<<<M, 256, 0, stream>>>(x, ln1_g + l*Cn, ln1_b + l*Cn, hA);
    tcvt_kernel<<<dim3(2304/32, 768/32), tb, 0, stream>>>(qkv_w + (size_t)l*Cn*3*Cn, wT, 768, 2304, 2304);
    gemm_kernel<3,128><<<dim3(M/128, 2304/128), 256, 0, stream>>>(hA, wT, qkv_b + (size_t)l*3*Cn, qkvh, nullptr, M, 2304, 768);
    vtrans_kernel<<<dim3(Tn/64, Bn*Hn), 256, 0, stream>>>(qkvh + 3*QKV_ELEMS, qkvh + 2*QKV_ELEMS);
    attn_kernel<<<dim3(128, Bn*Hn), 64, 0, stream>>>(qkvh, hA);
    tcvt_kernel<<<dim3(768/32, 768/32), tb, 0, stream>>>(aproj_w + (size_t)l*Cn*Cn, wT, 768, 768, 768);
    gemm_kernel<1,64><<<dim3(M/64, 768/128), 256, 0, stream>>>(hA, wT, aproj_b + (size_t)l*Cn, x, x, M, 768, 768);
    ln_kernel<<<M, 256, 0, stream>>>(x, ln2_g + l*Cn, ln2_b + l*Cn, hA);
    tcvt_kernel<<<dim3(3072/32, 768/32), tb, 0, stream>>>(fc_w + (size_t)l*Cn*4*Cn, wT, 768, 3072, 3072);
    gemm_kernel<2,128><<<dim3(M/128, 3072/128), 256, 0, stream>>>(hA, wT, fc_b + (size_t)l*4*Cn, hB, nullptr, M, 3072, 768);
    tcvt_kernel<<<dim3(768/32, 3072/32), tb, 0, stream>>>(mproj_w + (size_t)l*4*Cn*Cn, wT, 3072, 768, 768);
    gemm_kernel<1,64><<<dim3(M/64, 768/128), 256, 0, stream>>>(hB, wT, mproj_b + (size_t)l*Cn, x, x, M, 768, 3072);
  }
  ln_kernel<<<M, 256, 0, stream>>>(x, lnf_g, lnf_b, hA);
  tcvt_kernel<<<dim3(50432/32, 768/32), tb, 0, stream>>>(head_w, wT, 768, Vn, 50432);
  gemm256_kernel<<<dim3(M/256, 50432/256), 512, 0, stream>>>(hA, wT, nullptr, out, M, Vn, 768);
}

// Round 10
// 1796.358 us; speedup vs baseline: 1.2846x; 1.2846x over previous
//
#include <hip/hip_runtime.h>
#include <cstdint>
#include <cstddef>

#define Tn 2048
#define Bn 2
#define Hn 12
#define Cn 768
#define Ln 4
#define Vn 50257

typedef unsigned short ushort_t;
typedef __attribute__((ext_vector_type(8))) __bf16 bf16x8;
typedef __attribute__((ext_vector_type(8))) unsigned short u16x8;
typedef __attribute__((ext_vector_type(4))) float f32x4;

static constexpr size_t QKV_ELEMS = (size_t)Bn * Hn * Tn * 64;  // 3,145,728

__device__ inline unsigned short f2bf(float f) {
  unsigned int u = __float_as_uint(f);
  unsigned int r = (u + 0x7fffu + ((u >> 16) & 1u)) >> 16;
  return (unsigned short)r;
}

__device__ inline f32x4 zero4() { f32x4 z; z[0]=0.f; z[1]=0.f; z[2]=0.f; z[3]=0.f; return z; }

__device__ inline void gload_lds16(const ushort_t* g, ushort_t* l) {
  __builtin_amdgcn_global_load_lds(
      (const __attribute__((address_space(1))) void*)g,
      (__attribute__((address_space(3))) void*)l, 16, 0, 0);
}

// bijective XCD-chunked swizzle (m204)
__device__ inline int swz_lin() {
  int nbm = gridDim.x;
  int lin = blockIdx.y * nbm + blockIdx.x;
  int nwg = nbm * gridDim.y;
  int q = nwg >> 3, r = nwg & 7, x = lin & 7, p = lin >> 3;
  return (x < r ? x * (q + 1) : r * (q + 1) + (x - r) * q) + p;
}

// ---------------- embedding ----------------
__global__ __launch_bounds__(256) void embed_kernel(const int* __restrict__ idx,
    const float* __restrict__ tok, const float* __restrict__ pos, float* __restrict__ x) {
  int row = blockIdx.x;
  int t = row & (Tn - 1);
  int token = idx[row];
  const float* tr = tok + (size_t)token * Cn;
  const float* pr = pos + (size_t)t * Cn;
  float* xr = x + (size_t)row * Cn;
  for (int c = threadIdx.x; c < Cn; c += 256) xr[c] = tr[c] + pr[c];
}

// ---------------- layernorm -> bf16 ----------------
__global__ __launch_bounds__(256) void ln_kernel(const float* __restrict__ x,
    const float* __restrict__ gam, const float* __restrict__ bet, ushort_t* __restrict__ out) {
  int row = blockIdx.x;
  const float* xr = x + (size_t)row * Cn;
  float v[3]; float s = 0.f, s2 = 0.f;
  #pragma unroll
  for (int e = 0; e < 3; ++e) { float t = xr[threadIdx.x + e*256]; v[e] = t; s += t; s2 += t*t; }
  #pragma unroll
  for (int off = 32; off >= 1; off >>= 1) { s += __shfl_xor(s, off); s2 += __shfl_xor(s2, off); }
  __shared__ float red[8];
  int w = threadIdx.x >> 6;
  if ((threadIdx.x & 63) == 0) { red[w] = s; red[4 + w] = s2; }
  __syncthreads();
  s  = red[0] + red[1] + red[2] + red[3];
  s2 = red[4] + red[5] + red[6] + red[7];
  float mean = s * (1.f / Cn);
  float var  = s2 * (1.f / Cn) - mean * mean;
  float rstd = rsqrtf(var + 1e-5f);
  ushort_t* orow = out + (size_t)row * Cn;
  #pragma unroll
  for (int e = 0; e < 3; ++e) {
    int c = threadIdx.x + e*256;
    orow[c] = f2bf((v[e] - mean) * rstd * gam[c] + bet[c]);
  }
}

// ---------------- transpose + f32->bf16 weight conversion ----------------
__global__ __launch_bounds__(256) void tcvt_kernel(const float* __restrict__ in,
    ushort_t* __restrict__ out, int K, int N, int Npad) {
  __shared__ float tile[32][33];
  int n0 = blockIdx.x * 32, k0 = blockIdx.y * 32;
  int tx = threadIdx.x, ty = threadIdx.y;
  #pragma unroll
  for (int r = 0; r < 4; ++r) {
    int k = k0 + ty + 8*r;
    int n = n0 + tx;
    tile[ty + 8*r][tx] = (n < N) ? in[(size_t)k * N + n] : 0.f;
  }
  __syncthreads();
  #pragma unroll
  for (int r = 0; r < 4; ++r) {
    int n = n0 + ty + 8*r;
    out[(size_t)n * K + k0 + tx] = f2bf(tile[tx][ty + 8*r]);
  }
}

// ---------------- bf16 64x64 tile transpose: [BH,T,64] -> [BH,64,T] ----------------
__global__ __launch_bounds__(256) void vtrans_kernel(const ushort_t* __restrict__ vin,
                                                     ushort_t* __restrict__ vout) {
  __shared__ ushort_t tile[64][65];
  int t0 = blockIdx.x * 64;
  size_t bh = blockIdx.y;
  const ushort_t* src = vin + (bh * Tn + t0) * 64;
  int row = threadIdx.x >> 2, c0 = (threadIdx.x & 3) * 16;
  u16x8 a = *(const u16x8*)&src[(size_t)row * 64 + c0];
  u16x8 b = *(const u16x8*)&src[(size_t)row * 64 + c0 + 8];
  #pragma unroll
  for (int j = 0; j < 8; ++j) { tile[row][c0 + j] = a[j]; tile[row][c0 + 8 + j] = b[j]; }
  __syncthreads();
  int d = threadIdx.x >> 2, tq = (threadIdx.x & 3) * 16;
  u16x8 o0, o1;
  #pragma unroll
  for (int j = 0; j < 8; ++j) { o0[j] = tile[tq + j][d]; o1[j] = tile[tq + 8 + j][d]; }
  ushort_t* dst = vout + (bh * 64 + d) * Tn + t0 + tq;
  *(u16x8*)&dst[0] = o0;
  *(u16x8*)&dst[8] = o1;
}

// ======== 256x256 8-wave head GEMM: 3-buf LDS ring + T2 swizzle (r6 structure) ========
// C(MxN) f32 = A(MxK) * Bt^T (+bias); Bt (Npad x K) rows >= N zero-padded.
__global__ __launch_bounds__(512, 2) void gemm256_kernel(
    const ushort_t* __restrict__ A, const ushort_t* __restrict__ Bt,
    const float* __restrict__ bias, float* __restrict__ outp,
    int M, int N, int K) {
  __shared__ ushort_t lds[3 * 16384];   // 3 bufs x (A 16KB + B 16KB) = 96 KiB
  const int t = threadIdx.x;
  const int w = t >> 6, l = t & 63, lo = l & 15, g = l >> 4;
  const int wm = w >> 2, wn = w & 3;

  int bm, bn;
  {
    int seq = swz_lin();
    int gsz = 8 * gridDim.y;      // G=8 bm fast within supergroup; gridDim.x % 8 == 0
    int grp = seq / gsz;
    int t2 = seq - grp * gsz;
    bn = t2 >> 3;
    bm = grp * 8 + (t2 & 7);
  }

  const ushort_t* gAb = A  + (size_t)bm * 256 * K;
  const ushort_t* gBb = Bt + (size_t)bn * 256 * K;

  f32x4 acc[8][4];
  #pragma unroll
  for (int i = 0; i < 8; ++i)
    #pragma unroll
    for (int j = 0; j < 4; ++j) acc[i][j] = zero4();

  // stage tile kt into buf. LDS linear granule q=j*512+t -> row r=q>>2;
  // source col-granule = (q&3) ^ ((r>>1)&3)  [T2 inverse-swizzled SOURCE, rule #21]
  auto stage = [&](int kt, int buf) {
    const int k0 = kt << 5;
    #pragma unroll
    for (int j = 0; j < 2; ++j) {
      const int q = j * 512 + t;
      const int r = q >> 2;
      const int cc = ((q & 3) ^ ((r >> 1) & 3)) << 3;
      gload_lds16(gAb + (size_t)r * K + k0 + cc,
                  &lds[buf * 16384 + j * 4096 + w * 512]);
      gload_lds16(gBb + (size_t)r * K + k0 + cc,
                  &lds[buf * 16384 + 8192 + j * 4096 + w * 512]);
    }
  };
  const int csw = ((lo >> 1) & 3) << 3;   // read-side XOR, same involution
  auto compute = [&](int buf) {
    const ushort_t* as = &lds[buf * 16384];
    const ushort_t* bs = &lds[buf * 16384 + 8192];
    bf16x8 af[8], bfr[4];
    #pragma unroll
    for (int mi = 0; mi < 8; ++mi)
      af[mi] = *(const bf16x8*)&as[(wm*128 + mi*16 + lo) * 32 + ((g*8) ^ csw)];
    #pragma unroll
    for (int ni = 0; ni < 4; ++ni)
      bfr[ni] = *(const bf16x8*)&bs[(wn*64 + ni*16 + lo) * 32 + ((g*8) ^ csw)];
    __builtin_amdgcn_s_setprio(1);
    #pragma unroll
    for (int mi = 0; mi < 8; ++mi)
      #pragma unroll
      for (int ni = 0; ni < 4; ++ni)
        acc[mi][ni] = __builtin_amdgcn_mfma_f32_16x16x32_bf16(af[mi], bfr[ni], acc[mi][ni], 0, 0, 0);
    __builtin_amdgcn_s_setprio(0);
  };

  const int NK = K >> 5;
  stage(0, 0); stage(1, 1); stage(2, 2);
  asm volatile("s_waitcnt vmcnt(8)" ::: "memory");
  __builtin_amdgcn_s_barrier();

  int buf = 0;
  #pragma unroll 1
  for (int kt = 0; kt < NK; ++kt) {
    compute(buf);
    asm volatile("s_waitcnt lgkmcnt(0)" ::: "memory");
    __builtin_amdgcn_s_barrier();
    if (kt + 3 < NK) {
      stage(kt + 3, buf);
      asm volatile("s_waitcnt vmcnt(8)" ::: "memory");
    } else if (kt + 2 < NK) {
      asm volatile("s_waitcnt vmcnt(4)" ::: "memory");
    } else {
      asm volatile("s_waitcnt vmcnt(0)" ::: "memory");
    }
    __builtin_amdgcn_s_barrier();
    buf = (buf == 2) ? 0 : buf + 1;
  }

  #pragma unroll
  for (int mi = 0; mi < 8; ++mi) {
    #pragma unroll
    for (int ni = 0; ni < 4; ++ni) {
      int colg = bn*256 + wn*64 + ni*16 + lo;
      if (colg < N) {
        float bv = bias ? bias[colg] : 0.f;
        #pragma unroll
        for (int i = 0; i < 4; ++i) {
          int rowg = bm*256 + wm*128 + mi*16 + 4*g + i;
          outp[(size_t)rowg * N + colg] = acc[mi][ni][i] + bv;
        }
      }
    }
  }
}

// ---------------- GEMM (m97-style, 2-phase): C = A * Bt^T ----------------
// MODE 0: f32 = acc+bias ; 1: f32 = res+acc+bias ; 2: bf16 = gelu(acc+bias)
// MODE 3: q [B,H,T,64] (x0.125), k [B,H,T,64], v [B,H,T,64] (coalesced; vtrans later)
template<int MODE, int TM>
__global__ __launch_bounds__(256) void gemm_kernel(
    const ushort_t* __restrict__ A, const ushort_t* __restrict__ Bt,
    const float* __restrict__ bias, void* __restrict__ outp,
    const float* __restrict__ res, int M, int N, int K) {
  constexpr int MI = TM / 32;
  constexpr int ABUF = TM * 32;
  __shared__ ushort_t As[2 * ABUF];
  __shared__ ushort_t Bs[2 * 4096];
  const int t = threadIdx.x;
  int bm, bn;
  {
    int seq = swz_lin();
    const int G = 8;
    int NBN = gridDim.y;
    int gsz = G * NBN;
    int grp = seq / gsz;
    int t2 = seq - grp * gsz;
    bn = t2 / G;
    bm = grp * G + (t2 - bn * G);
  }
  const int w = t >> 6, l = t & 63, lo = l & 15, g = l >> 4;
  const int wm = w >> 1, wn = w & 1;

  f32x4 acc[MI][4];
  #pragma unroll
  for (int i = 0; i < MI; ++i)
    #pragma unroll
    for (int j = 0; j < 4; ++j) acc[i][j] = zero4();

  const int srow = t >> 2;
  const int scol = (t & 3) * 8;
  const ushort_t* gA = A  + (size_t)(bm * TM  + srow) * K + scol;
  const ushort_t* gB = Bt + (size_t)(bn * 128 + srow) * K + scol;
  ushort_t* lA = As + w * 512;
  ushort_t* lB = Bs + w * 512;

  auto stage = [&](int buf, int k0) {
    gload_lds16(gA + k0, lA + buf * ABUF);
    if (TM == 128) gload_lds16(gA + (size_t)64 * K + k0, lA + buf * ABUF + 2048);
    gload_lds16(gB + k0, lB + buf * 4096);
    gload_lds16(gB + (size_t)64 * K + k0, lB + buf * 4096 + 2048);
  };
  auto compute = [&](int buf) {
    const ushort_t* as = As + buf * ABUF;
    const ushort_t* bs = Bs + buf * 4096;
    bf16x8 af[MI], bfr[4];
    #pragma unroll
    for (int mi = 0; mi < MI; ++mi)
      af[mi] = *(const bf16x8*)&as[(size_t)(wm*(TM/2) + mi*16 + lo) * 32 + g*8];
    #pragma unroll
    for (int ni = 0; ni < 4; ++ni)
      bfr[ni] = *(const bf16x8*)&bs[(size_t)(wn*64 + ni*16 + lo) * 32 + g*8];
    #pragma unroll
    for (int mi = 0; mi < MI; ++mi)
      #pragma unroll
      for (int ni = 0; ni < 4; ++ni)
        acc[mi][ni] = __builtin_amdgcn_mfma_f32_16x16x32_bf16(af[mi], bfr[ni], acc[mi][ni], 0, 0, 0);
  };

  const int NK = K >> 5;
  stage(0, 0);
  __syncthreads();
  for (int kk = 0; kk < NK - 1; ++kk) {
    stage((kk + 1) & 1, (kk + 1) << 5);
    compute(kk & 1);
    __syncthreads();
  }
  compute((NK - 1) & 1);

  #pragma unroll
  for (int mi = 0; mi < MI; ++mi) {
    #pragma unroll
    for (int ni = 0; ni < 4; ++ni) {
      int colg = bn*128 + wn*64 + ni*16 + lo;
      if (colg < N) {
        float bv = bias ? bias[colg] : 0.f;
        #pragma unroll
        for (int i = 0; i < 4; ++i) {
          int rowg = bm*TM + wm*(TM/2) + mi*16 + 4*g + i;
          float vv = acc[mi][ni][i] + bv;
          if (MODE == 0) {
            ((float*)outp)[(size_t)rowg * N + colg] = vv;
          } else if (MODE == 1) {
            size_t off = (size_t)rowg * N + colg;
            ((float*)outp)[off] = res[off] + vv;
          } else if (MODE == 2) {
            float ge = 0.5f * vv * (1.f + erff(vv * 0.70710678118f));
            ((ushort_t*)outp)[(size_t)rowg * N + colg] = f2bf(ge);
          } else {
            int which = colg / Cn;
            int rem = colg - which * Cn;
            int h = rem >> 6, d = rem & 63;
            int b = rowg >> 11, tt = rowg & (Tn - 1);
            ushort_t* qb = (ushort_t*)outp;
            size_t bh = (size_t)(b * Hn + h);
            size_t off = (bh * Tn + tt) * 64 + d;
            if (which == 0)      qb[off] = f2bf(vv * 0.125f);
            else if (which == 1) qb[QKV_ELEMS + off] = f2bf(vv);
            else                 qb[3*QKV_ELEMS + off] = f2bf(vv);   // staging; vtrans -> 2*QKV
          }
        }
      }
    }
  }
}

// ---------------- flash attention (causal), 1 wave / 16 q-rows, no LDS ----------------
// + T12 cvt_pk pack, + T13 defer-max (wave-uniform skip)
__global__ __launch_bounds__(64) void attn_kernel(const ushort_t* __restrict__ qkvh,
                                                  ushort_t* __restrict__ y) {
  const int l = threadIdx.x;
  const int lo = l & 15, g = l >> 4;
  int nl = swz_lin();
  const int qt = nl & 127;
  const int bh = nl >> 7;
  const int b = bh / Hn, h = bh % Hn;
  const int q0 = qt * 16;
  const ushort_t* Qp = qkvh + (size_t)bh * Tn * 64;
  const ushort_t* Kp = qkvh + QKV_ELEMS + (size_t)bh * Tn * 64;
  const ushort_t* Vt = qkvh + 2*QKV_ELEMS + (size_t)bh * 64 * Tn;

  bf16x8 qf[2];
  #pragma unroll
  for (int ch = 0; ch < 2; ++ch)
    qf[ch] = *(const bf16x8*)&Qp[(size_t)(q0 + lo) * 64 + ch*32 + g*8];

  f32x4 of[4];
  #pragma unroll
  for (int ch = 0; ch < 4; ++ch) of[ch] = zero4();
  float m = -1e30f, lsum = 0.f;
  const int nkv = q0 + 16;
  const bool ghi = (g >= 2);
  const int lg2 = (g & 1) * 32;

  for (int kv0 = 0; kv0 < nkv; kv0 += 32) {
    bf16x8 vf[4];
    #pragma unroll
    for (int ch = 0; ch < 4; ++ch)
      vf[ch] = *(const bf16x8*)&Vt[(size_t)(ch*16 + lo) * Tn + kv0 + g*8];

    float s8[8];
    #pragma unroll
    for (int sub = 0; sub < 2; ++sub) {
      int kvb = kv0 + 16*sub;
      bf16x8 kf[2];
      #pragma unroll
      for (int ch = 0; ch < 2; ++ch)
        kf[ch] = *(const bf16x8*)&Kp[(size_t)(kvb + lo) * 64 + ch*32 + g*8];
      f32x4 st = zero4();
      st = __builtin_amdgcn_mfma_f32_16x16x32_bf16(kf[0], qf[0], st, 0, 0, 0);
      st = __builtin_amdgcn_mfma_f32_16x16x32_bf16(kf[1], qf[1], st, 0, 0, 0);
      #pragma unroll
      for (int i = 0; i < 4; ++i) {
        int kvi = kvb + 4*g + i;
        s8[sub*4 + i] = (kvi <= q0 + lo) ? st[i] : -1e30f;
      }
    }
    float tmax = s8[0];
    #pragma unroll
    for (int j = 1; j < 8; ++j) tmax = fmaxf(tmax, s8[j]);
    tmax = fmaxf(tmax, __shfl_xor(tmax, 16));
    tmax = fmaxf(tmax, __shfl_xor(tmax, 32));
    // T13 defer-max: if no row's max grew, skip rescale entirely (P = exp(s-m) <= 1)
    if (!__all(tmax <= m)) {
      float newm = fmaxf(m, tmax);
      float resc = __expf(m - newm);
      lsum *= resc;
      m = newm;
      #pragma unroll
      for (int i = 0; i < 4; ++i) {
        float rs = __shfl(resc, 4*g + i);
        of[0][i] *= rs; of[1][i] *= rs; of[2][i] *= rs; of[3][i] *= rs;
      }
    }
    float p8[8]; float psum = 0.f;
    #pragma unroll
    for (int j = 0; j < 8; ++j) { p8[j] = __expf(s8[j] - m); psum += p8[j]; }
    psum += __shfl_xor(psum, 16);
    psum += __shfl_xor(psum, 32);
    lsum += psum;
    // T12: pack P to bf16 pairs with v_cvt_pk_bf16_f32
    unsigned int q4[4];
    #pragma unroll
    for (int c = 0; c < 4; ++c)
      asm("v_cvt_pk_bf16_f32 %0, %1, %2" : "=v"(q4[c]) : "v"(p8[2*c]), "v"(p8[2*c+1]));
    union { unsigned int wv[4]; bf16x8 v; } pu;
    #pragma unroll
    for (int j = 0; j < 4; ++j) {
      int srcLane = lo + lg2 + ((j >> 1) << 4);
      unsigned int lo_w = (unsigned int)__shfl((int)q4[j & 1], srcLane);
      unsigned int hi_w = (unsigned int)__shfl((int)q4[2 + (j & 1)], srcLane);
      pu.wv[j] = ghi ? hi_w : lo_w;
    }
    #pragma unroll
    for (int ch = 0; ch < 4; ++ch)
      of[ch] = __builtin_amdgcn_mfma_f32_16x16x32_bf16(pu.v, vf[ch], of[ch], 0, 0, 0);
  }

  #pragma unroll
  for (int i = 0; i < 4; ++i) {
    float li = 1.f / __shfl(lsum, 4*g + i);
    of[0][i] *= li; of[1][i] *= li; of[2][i] *= li; of[3][i] *= li;
  }
  ushort_t* yb = y + ((size_t)b*Tn + q0) * Cn + h*64;
  #pragma unroll
  for (int ch = 0; ch < 4; ++ch)
    #pragma unroll
    for (int i = 0; i < 4; ++i)
      yb[(size_t)(4*g + i) * Cn + ch*16 + lo] = f2bf(of[ch][i]);
}

// ---------------- launch ----------------
extern "C" void kernel_launch(void* const* d_in, const int* in_sizes, int n_in,
                              void* d_out, int out_size, void* d_ws, size_t ws_size,
                              hipStream_t stream) {
  const int*   idx     = (const int*)d_in[0];
  const float* tok_emb = (const float*)d_in[1];
  const float* pos_emb = (const float*)d_in[2];
  const float* ln1_g   = (const float*)d_in[3];
  const float* ln1_b   = (const float*)d_in[4];
  const float* qkv_w   = (const float*)d_in[5];
  const float* qkv_b   = (const float*)d_in[6];
  const float* aproj_w = (const float*)d_in[7];
  const float* aproj_b = (const float*)d_in[8];
  const float* ln2_g   = (const float*)d_in[9];
  const float* ln2_b   = (const float*)d_in[10];
  const float* fc_w    = (const float*)d_in[11];
  const float* fc_b    = (const float*)d_in[12];
  const float* mproj_w = (const float*)d_in[13];
  const float* mproj_b = (const float*)d_in[14];
  const float* lnf_g   = (const float*)d_in[15];
  const float* lnf_b   = (const float*)d_in[16];
  const float* head_w  = (const float*)d_in[17];
  float* out = (float*)d_out;

  char* ws = (char*)d_ws;
  float*    x    = (float*)(ws);                         // 12,582,912 B
  ushort_t* hA   = (ushort_t*)(ws + 12582912);           //  6,291,456 B
  ushort_t* hB   = (ushort_t*)(ws + 18874368);           // 25,165,824 B
  ushort_t* qkvh = (ushort_t*)(ws + 44040192);           // 25,165,824 B (q,k,vT,vtmp)
  ushort_t* wT   = (ushort_t*)(ws + 69206016);           // 77,463,552 B (Npad 50432)

  const int M = Bn * Tn;  // 4096
  dim3 tb(32, 8);

  embed_kernel<<<M, 256, 0, stream>>>(idx, tok_emb, pos_emb, x);
  for (int l = 0; l < Ln; ++l) {
    ln_kernel<<<M, 256, 0, stream>>>(x, ln1_g + l*Cn, ln1_b + l*Cn, hA);
    tcvt_kernel<<<dim3(2304/32, 768/32), tb, 0, stream>>>(qkv_w + (size_t)l*Cn*3*Cn, wT, 768, 2304, 2304);
    gemm_kernel<3,128><<<dim3(M/128, 2304/128), 256, 0, stream>>>(hA, wT, qkv_b + (size_t)l*3*Cn, qkvh, nullptr, M, 2304, 768);
    vtrans_kernel<<<dim3(Tn/64, Bn*Hn), 256, 0, stream>>>(qkvh + 3*QKV_ELEMS, qkvh + 2*QKV_ELEMS);
    attn_kernel<<<dim3(128, Bn*Hn), 64, 0, stream>>>(qkvh, hA);
    tcvt_kernel<<<dim3(768/32, 768/32), tb, 0, stream>>>(aproj_w + (size_t)l*Cn*Cn, wT, 768, 768, 768);
    gemm_kernel<1,64><<<dim3(M/64, 768/128), 256, 0, stream>>>(hA, wT, aproj_b + (size_t)l*Cn, x, x, M, 768, 768);
    ln_kernel<<<M, 256, 0, stream>>>(x, ln2_g + l*Cn, ln2_b + l*Cn, hA);
    tcvt_kernel<<<dim3(3072/32, 768/32), tb, 0, stream>>>(fc_w + (size_t)l*Cn*4*Cn, wT, 768, 3072, 3072);
    gemm_kernel<2,128><<<dim3(M/128, 3072/128), 256, 0, stream>>>(hA, wT, fc_b + (size_t)l*4*Cn, hB, nullptr, M, 3072, 768);
    tcvt_kernel<<<dim3(768/32, 3072/32), tb, 0, stream>>>(mproj_w + (size_t)l*4*Cn*Cn, wT, 3072, 768, 768);
    gemm_kernel<1,64><<<dim3(M/64, 768/128), 256, 0, stream>>>(hB, wT, mproj_b + (size_t)l*Cn, x, x, M, 768, 3072);
  }
  ln_kernel<<<M, 256, 0, stream>>>(x, lnf_g, lnf_b, hA);
  tcvt_kernel<<<dim3(50432/32, 768/32), tb, 0, stream>>>(head_w, wT, 768, Vn, 50432);
  gemm256_kernel<<<dim3(M/256, 50432/256), 512, 0, stream>>>(hA, wT, nullptr, out, M, Vn, 768);
}

// Round 11
// 1690.888 us; speedup vs baseline: 1.3647x; 1.0624x over previous
//
#include <hip/hip_runtime.h>
#include <cstdint>
#include <cstddef>

#define Tn 2048
#define Bn 2
#define Hn 12
#define Cn 768
#define Ln 4
#define Vn 50257

typedef unsigned short ushort_t;
typedef __attribute__((ext_vector_type(8))) __bf16 bf16x8;
typedef __attribute__((ext_vector_type(8))) unsigned short u16x8;
typedef __attribute__((ext_vector_type(4))) unsigned short u16x4;
typedef __attribute__((ext_vector_type(4))) float f32x4;

static constexpr size_t QKV_ELEMS = (size_t)Bn * Hn * Tn * 64;  // 3,145,728
// merged per-layer weight^T offsets (elems) inside wT
static constexpr size_t OFF_QKV = 0;
static constexpr size_t OFF_APROJ = 1769472;   // 2304*768
static constexpr size_t OFF_FC = 2359296;      // + 768*768
static constexpr size_t OFF_MPROJ = 4718592;   // + 3072*768

__device__ inline unsigned short f2bf(float f) {
  unsigned int u = __float_as_uint(f);
  unsigned int r = (u + 0x7fffu + ((u >> 16) & 1u)) >> 16;
  return (unsigned short)r;
}

__device__ inline f32x4 zero4() { f32x4 z; z[0]=0.f; z[1]=0.f; z[2]=0.f; z[3]=0.f; return z; }

__device__ inline void gload_lds16(const ushort_t* g, ushort_t* l) {
  __builtin_amdgcn_global_load_lds(
      (const __attribute__((address_space(1))) void*)g,
      (__attribute__((address_space(3))) void*)l, 16, 0, 0);
}

// bijective XCD-chunked swizzle (m204)
__device__ inline int swz_lin() {
  int nbm = gridDim.x;
  int lin = blockIdx.y * nbm + blockIdx.x;
  int nwg = nbm * gridDim.y;
  int q = nwg >> 3, r = nwg & 7, x = lin & 7, p = lin >> 3;
  return (x < r ? x * (q + 1) : r * (q + 1) + (x - r) * q) + p;
}

// ---------------- embedding (float4) ----------------
__global__ __launch_bounds__(192) void embed_kernel(const int* __restrict__ idx,
    const float* __restrict__ tok, const float* __restrict__ pos, float* __restrict__ x) {
  int row = blockIdx.x;
  int t = row & (Tn - 1);
  int token = idx[row];
  const f32x4* tr = (const f32x4*)(tok + (size_t)token * Cn);
  const f32x4* pr = (const f32x4*)(pos + (size_t)t * Cn);
  f32x4* xr = (f32x4*)(x + (size_t)row * Cn);
  xr[threadIdx.x] = tr[threadIdx.x] + pr[threadIdx.x];
}

// ---------------- layernorm -> bf16 (wave per row, float4) ----------------
__global__ __launch_bounds__(256) void ln_kernel(const float* __restrict__ x,
    const float* __restrict__ gam, const float* __restrict__ bet, ushort_t* __restrict__ out) {
  const int wv = threadIdx.x >> 6, lane = threadIdx.x & 63;
  const int row = blockIdx.x * 4 + wv;
  const f32x4* xr = (const f32x4*)(x + (size_t)row * Cn);
  f32x4 v[3]; float s = 0.f, s2 = 0.f;
  #pragma unroll
  for (int e = 0; e < 3; ++e) {
    v[e] = xr[lane + e*64];
    #pragma unroll
    for (int j = 0; j < 4; ++j) { s += v[e][j]; s2 += v[e][j]*v[e][j]; }
  }
  #pragma unroll
  for (int off = 32; off >= 1; off >>= 1) { s += __shfl_xor(s, off); s2 += __shfl_xor(s2, off); }
  float mean = s * (1.f / Cn);
  float var  = s2 * (1.f / Cn) - mean * mean;
  float rstd = rsqrtf(var + 1e-5f);
  const f32x4* g4 = (const f32x4*)gam;
  const f32x4* b4 = (const f32x4*)bet;
  u16x4* o4 = (u16x4*)(out + (size_t)row * Cn);
  #pragma unroll
  for (int e = 0; e < 3; ++e) {
    f32x4 gv = g4[lane + e*64], bv = b4[lane + e*64];
    u16x4 o;
    #pragma unroll
    for (int j = 0; j < 4; ++j) o[j] = f2bf((v[e][j] - mean) * rstd * gv[j] + bv[j]);
    o4[lane + e*64] = o;
  }
}

// ---------------- transpose + f32->bf16 (head weight) ----------------
__global__ __launch_bounds__(256) void tcvt_kernel(const float* __restrict__ in,
    ushort_t* __restrict__ out, int K, int N, int Npad) {
  __shared__ float tile[32][33];
  int n0 = blockIdx.x * 32, k0 = blockIdx.y * 32;
  int tx = threadIdx.x, ty = threadIdx.y;
  #pragma unroll
  for (int r = 0; r < 4; ++r) {
    int k = k0 + ty + 8*r;
    int n = n0 + tx;
    tile[ty + 8*r][tx] = (n < N) ? in[(size_t)k * N + n] : 0.f;
  }
  __syncthreads();
  #pragma unroll
  for (int r = 0; r < 4; ++r) {
    int n = n0 + ty + 8*r;
    out[(size_t)n * K + k0 + tx] = f2bf(tile[tx][ty + 8*r]);
  }
}

// ---------------- merged per-layer weight transpose+convert (4 mats, 1 launch) ----------------
__global__ __launch_bounds__(256) void tcvt4_kernel(const float* __restrict__ qkvp,
    const float* __restrict__ aprojp, const float* __restrict__ fcp,
    const float* __restrict__ mprojp, ushort_t* __restrict__ wT) {
  __shared__ float tile[32][33];
  int bid = blockIdx.x;
  const float* in; int K, N, tilesX, local; size_t ooff;
  if (bid < 1728)      { in = qkvp;   K = 768;  N = 2304; tilesX = 72; ooff = OFF_QKV;   local = bid; }
  else if (bid < 2304) { in = aprojp; K = 768;  N = 768;  tilesX = 24; ooff = OFF_APROJ; local = bid - 1728; }
  else if (bid < 4608) { in = fcp;    K = 768;  N = 3072; tilesX = 96; ooff = OFF_FC;    local = bid - 2304; }
  else                 { in = mprojp; K = 3072; N = 768;  tilesX = 24; ooff = OFF_MPROJ; local = bid - 4608; }
  int n0 = (local % tilesX) * 32, k0 = (local / tilesX) * 32;
  int tx = threadIdx.x, ty = threadIdx.y;
  ushort_t* out = wT + ooff;
  #pragma unroll
  for (int r = 0; r < 4; ++r)
    tile[ty + 8*r][tx] = in[(size_t)(k0 + ty + 8*r) * N + n0 + tx];
  __syncthreads();
  #pragma unroll
  for (int r = 0; r < 4; ++r)
    out[(size_t)(n0 + ty + 8*r) * K + k0 + tx] = f2bf(tile[tx][ty + 8*r]);
}

// ---------------- bf16 64x64 tile transpose: [BH,T,64] -> [BH,64,T] ----------------
__global__ __launch_bounds__(256) void vtrans_kernel(const ushort_t* __restrict__ vin,
                                                     ushort_t* __restrict__ vout) {
  __shared__ ushort_t tile[64][65];
  int t0 = blockIdx.x * 64;
  size_t bh = blockIdx.y;
  const ushort_t* src = vin + (bh * Tn + t0) * 64;
  int row = threadIdx.x >> 2, c0 = (threadIdx.x & 3) * 16;
  u16x8 a = *(const u16x8*)&src[(size_t)row * 64 + c0];
  u16x8 b = *(const u16x8*)&src[(size_t)row * 64 + c0 + 8];
  #pragma unroll
  for (int j = 0; j < 8; ++j) { tile[row][c0 + j] = a[j]; tile[row][c0 + 8 + j] = b[j]; }
  __syncthreads();
  int d = threadIdx.x >> 2, tq = (threadIdx.x & 3) * 16;
  u16x8 o0, o1;
  #pragma unroll
  for (int j = 0; j < 8; ++j) { o0[j] = tile[tq + j][d]; o1[j] = tile[tq + 8 + j][d]; }
  ushort_t* dst = vout + (bh * 64 + d) * Tn + t0 + tq;
  *(u16x8*)&dst[0] = o0;
  *(u16x8*)&dst[8] = o1;
}

// ======== 256x256 8-wave head GEMM: 3-buf LDS ring + T2 swizzle (r10, best measured) ========
__global__ __launch_bounds__(512, 2) void gemm256_kernel(
    const ushort_t* __restrict__ A, const ushort_t* __restrict__ Bt,
    const float* __restrict__ bias, float* __restrict__ outp,
    int M, int N, int K) {
  __shared__ ushort_t lds[3 * 16384];
  const int t = threadIdx.x;
  const int w = t >> 6, l = t & 63, lo = l & 15, g = l >> 4;
  const int wm = w >> 2, wn = w & 3;

  int bm, bn;
  {
    int seq = swz_lin();
    int gsz = 8 * gridDim.y;
    int grp = seq / gsz;
    int t2 = seq - grp * gsz;
    bn = t2 >> 3;
    bm = grp * 8 + (t2 & 7);
  }

  const ushort_t* gAb = A  + (size_t)bm * 256 * K;
  const ushort_t* gBb = Bt + (size_t)bn * 256 * K;

  f32x4 acc[8][4];
  #pragma unroll
  for (int i = 0; i < 8; ++i)
    #pragma unroll
    for (int j = 0; j < 4; ++j) acc[i][j] = zero4();

  auto stage = [&](int kt, int buf) {
    const int k0 = kt << 5;
    #pragma unroll
    for (int j = 0; j < 2; ++j) {
      const int q = j * 512 + t;
      const int r = q >> 2;
      const int cc = ((q & 3) ^ ((r >> 1) & 3)) << 3;
      gload_lds16(gAb + (size_t)r * K + k0 + cc,
                  &lds[buf * 16384 + j * 4096 + w * 512]);
      gload_lds16(gBb + (size_t)r * K + k0 + cc,
                  &lds[buf * 16384 + 8192 + j * 4096 + w * 512]);
    }
  };
  const int csw = ((lo >> 1) & 3) << 3;
  auto compute = [&](int buf) {
    const ushort_t* as = &lds[buf * 16384];
    const ushort_t* bs = &lds[buf * 16384 + 8192];
    bf16x8 af[8], bfr[4];
    #pragma unroll
    for (int mi = 0; mi < 8; ++mi)
      af[mi] = *(const bf16x8*)&as[(wm*128 + mi*16 + lo) * 32 + ((g*8) ^ csw)];
    #pragma unroll
    for (int ni = 0; ni < 4; ++ni)
      bfr[ni] = *(const bf16x8*)&bs[(wn*64 + ni*16 + lo) * 32 + ((g*8) ^ csw)];
    __builtin_amdgcn_s_setprio(1);
    #pragma unroll
    for (int mi = 0; mi < 8; ++mi)
      #pragma unroll
      for (int ni = 0; ni < 4; ++ni)
        acc[mi][ni] = __builtin_amdgcn_mfma_f32_16x16x32_bf16(af[mi], bfr[ni], acc[mi][ni], 0, 0, 0);
    __builtin_amdgcn_s_setprio(0);
  };

  const int NK = K >> 5;
  stage(0, 0); stage(1, 1); stage(2, 2);
  asm volatile("s_waitcnt vmcnt(8)" ::: "memory");
  __builtin_amdgcn_s_barrier();

  int buf = 0;
  #pragma unroll 1
  for (int kt = 0; kt < NK; ++kt) {
    compute(buf);
    asm volatile("s_waitcnt lgkmcnt(0)" ::: "memory");
    __builtin_amdgcn_s_barrier();
    if (kt + 3 < NK) {
      stage(kt + 3, buf);
      asm volatile("s_waitcnt vmcnt(8)" ::: "memory");
    } else if (kt + 2 < NK) {
      asm volatile("s_waitcnt vmcnt(4)" ::: "memory");
    } else {
      asm volatile("s_waitcnt vmcnt(0)" ::: "memory");
    }
    __builtin_amdgcn_s_barrier();
    buf = (buf == 2) ? 0 : buf + 1;
  }

  #pragma unroll
  for (int mi = 0; mi < 8; ++mi) {
    #pragma unroll
    for (int ni = 0; ni < 4; ++ni) {
      int colg = bn*256 + wn*64 + ni*16 + lo;
      if (colg < N) {
        float bv = bias ? bias[colg] : 0.f;
        #pragma unroll
        for (int i = 0; i < 4; ++i) {
          int rowg = bm*256 + wm*128 + mi*16 + 4*g + i;
          outp[(size_t)rowg * N + colg] = acc[mi][ni][i] + bv;
        }
      }
    }
  }
}

// ======== layer GEMM: 3-buf counted-vmcnt ring + T2 swizzle (r10-head pattern @ 128/64 tile) ========
// MODE 1: f32 = res+acc+bias ; 2: bf16 = gelu(acc+bias)
// MODE 3: q [B,H,T,64] (x0.125), k [B,H,T,64], v [B,H,T,64] (coalesced; vtrans later)
template<int MODE, int TM>
__global__ __launch_bounds__(256) void gemm_kernel(
    const ushort_t* __restrict__ A, const ushort_t* __restrict__ Bt,
    const float* __restrict__ bias, void* __restrict__ outp,
    const float* __restrict__ res, int M, int N, int K) {
  constexpr int MI = TM / 32;
  constexpr int ASZ = TM * 32;           // elems per A tile
  constexpr int BUFE = ASZ + 4096;       // elems per ring slot (A + B[128][32])
  constexpr int LPT = TM/64 + 2;         // gloads per thread per tile (4 or 3)
  __shared__ ushort_t lds[3 * BUFE];
  const int t = threadIdx.x;
  int bm, bn;
  {
    int seq = swz_lin();
    const int G = 8;
    int gsz = G * gridDim.y;
    int grp = seq / gsz;
    int t2 = seq - grp * gsz;
    bn = t2 / G;
    bm = grp * G + (t2 - bn * G);
  }
  const int w = t >> 6, l = t & 63, lo = l & 15, g = l >> 4;
  const int wm = w >> 1, wn = w & 1;

  f32x4 acc[MI][4];
  #pragma unroll
  for (int i = 0; i < MI; ++i)
    #pragma unroll
    for (int j = 0; j < 4; ++j) acc[i][j] = zero4();

  const ushort_t* gAb = A  + (size_t)bm * TM * K;
  const ushort_t* gBb = Bt + (size_t)bn * 128 * K;

  auto stage = [&](int kt, int buf) {
    const int k0 = kt << 5;
    #pragma unroll
    for (int j = 0; j < TM/64; ++j) {
      const int q = j * 256 + t;
      const int r = q >> 2;
      const int cc = ((q & 3) ^ ((r >> 1) & 3)) << 3;
      gload_lds16(gAb + (size_t)r * K + k0 + cc, &lds[buf*BUFE + (j*256 + w*64)*8]);
    }
    #pragma unroll
    for (int j = 0; j < 2; ++j) {
      const int q = j * 256 + t;
      const int r = q >> 2;
      const int cc = ((q & 3) ^ ((r >> 1) & 3)) << 3;
      gload_lds16(gBb + (size_t)r * K + k0 + cc, &lds[buf*BUFE + ASZ + (j*256 + w*64)*8]);
    }
  };
  const int csw = ((lo >> 1) & 3) << 3;
  auto compute = [&](int buf) {
    const ushort_t* as = &lds[buf * BUFE];
    const ushort_t* bs = &lds[buf * BUFE + ASZ];
    bf16x8 af[MI], bfr[4];
    #pragma unroll
    for (int mi = 0; mi < MI; ++mi)
      af[mi] = *(const bf16x8*)&as[(wm*(TM/2) + mi*16 + lo) * 32 + ((g*8) ^ csw)];
    #pragma unroll
    for (int ni = 0; ni < 4; ++ni)
      bfr[ni] = *(const bf16x8*)&bs[(wn*64 + ni*16 + lo) * 32 + ((g*8) ^ csw)];
    __builtin_amdgcn_s_setprio(1);
    #pragma unroll
    for (int mi = 0; mi < MI; ++mi)
      #pragma unroll
      for (int ni = 0; ni < 4; ++ni)
        acc[mi][ni] = __builtin_amdgcn_mfma_f32_16x16x32_bf16(af[mi], bfr[ni], acc[mi][ni], 0, 0, 0);
    __builtin_amdgcn_s_setprio(0);
  };

  const int NK = K >> 5;
  stage(0, 0); stage(1, 1); stage(2, 2);
  if constexpr (LPT == 4) asm volatile("s_waitcnt vmcnt(8)" ::: "memory");
  else                    asm volatile("s_waitcnt vmcnt(6)" ::: "memory");
  __builtin_amdgcn_s_barrier();

  int buf = 0;
  #pragma unroll 1
  for (int kt = 0; kt < NK; ++kt) {
    compute(buf);
    asm volatile("s_waitcnt lgkmcnt(0)" ::: "memory");
    __builtin_amdgcn_s_barrier();
    if (kt + 3 < NK) {
      stage(kt + 3, buf);
      if constexpr (LPT == 4) asm volatile("s_waitcnt vmcnt(8)" ::: "memory");
      else                    asm volatile("s_waitcnt vmcnt(6)" ::: "memory");
    } else if (kt + 2 < NK) {
      if constexpr (LPT == 4) asm volatile("s_waitcnt vmcnt(4)" ::: "memory");
      else                    asm volatile("s_waitcnt vmcnt(3)" ::: "memory");
    } else {
      asm volatile("s_waitcnt vmcnt(0)" ::: "memory");
    }
    __builtin_amdgcn_s_barrier();
    buf = (buf == 2) ? 0 : buf + 1;
  }

  #pragma unroll
  for (int mi = 0; mi < MI; ++mi) {
    #pragma unroll
    for (int ni = 0; ni < 4; ++ni) {
      int colg = bn*128 + wn*64 + ni*16 + lo;
      if (colg < N) {
        float bv = bias ? bias[colg] : 0.f;
        #pragma unroll
        for (int i = 0; i < 4; ++i) {
          int rowg = bm*TM + wm*(TM/2) + mi*16 + 4*g + i;
          float vv = acc[mi][ni][i] + bv;
          if (MODE == 1) {
            size_t off = (size_t)rowg * N + colg;
            ((float*)outp)[off] = res[off] + vv;
          } else if (MODE == 2) {
            float ge = 0.5f * vv * (1.f + erff(vv * 0.70710678118f));
            ((ushort_t*)outp)[(size_t)rowg * N + colg] = f2bf(ge);
          } else {
            int which = colg / Cn;
            int rem = colg - which * Cn;
            int h = rem >> 6, d = rem & 63;
            int b = rowg >> 11, tt = rowg & (Tn - 1);
            ushort_t* qb = (ushort_t*)outp;
            size_t bh = (size_t)(b * Hn + h);
            size_t off = (bh * Tn + tt) * 64 + d;
            if (which == 0)      qb[off] = f2bf(vv * 0.125f);
            else if (which == 1) qb[QKV_ELEMS + off] = f2bf(vv);
            else                 qb[3*QKV_ELEMS + off] = f2bf(vv);   // staging; vtrans -> 2*QKV
          }
        }
      }
    }
  }
}

// ---------------- flash attention (causal), 1 wave / 16 q-rows, no LDS ----------------
__global__ __launch_bounds__(64) void attn_kernel(const ushort_t* __restrict__ qkvh,
                                                  ushort_t* __restrict__ y) {
  const int l = threadIdx.x;
  const int lo = l & 15, g = l >> 4;
  int nl = swz_lin();
  const int qt = nl & 127;
  const int bh = nl >> 7;
  const int b = bh / Hn, h = bh % Hn;
  const int q0 = qt * 16;
  const ushort_t* Qp = qkvh + (size_t)bh * Tn * 64;
  const ushort_t* Kp = qkvh + QKV_ELEMS + (size_t)bh * Tn * 64;
  const ushort_t* Vt = qkvh + 2*QKV_ELEMS + (size_t)bh * 64 * Tn;

  bf16x8 qf[2];
  #pragma unroll
  for (int ch = 0; ch < 2; ++ch)
    qf[ch] = *(const bf16x8*)&Qp[(size_t)(q0 + lo) * 64 + ch*32 + g*8];

  f32x4 of[4];
  #pragma unroll
  for (int ch = 0; ch < 4; ++ch) of[ch] = zero4();
  float m = -1e30f, lsum = 0.f;
  const int nkv = q0 + 16;
  const bool ghi = (g >= 2);
  const int lg2 = (g & 1) * 32;

  for (int kv0 = 0; kv0 < nkv; kv0 += 32) {
    bf16x8 vf[4];
    #pragma unroll
    for (int ch = 0; ch < 4; ++ch)
      vf[ch] = *(const bf16x8*)&Vt[(size_t)(ch*16 + lo) * Tn + kv0 + g*8];

    float s8[8];
    #pragma unroll
    for (int sub = 0; sub < 2; ++sub) {
      int kvb = kv0 + 16*sub;
      bf16x8 kf[2];
      #pragma unroll
      for (int ch = 0; ch < 2; ++ch)
        kf[ch] = *(const bf16x8*)&Kp[(size_t)(kvb + lo) * 64 + ch*32 + g*8];
      f32x4 st = zero4();
      st = __builtin_amdgcn_mfma_f32_16x16x32_bf16(kf[0], qf[0], st, 0, 0, 0);
      st = __builtin_amdgcn_mfma_f32_16x16x32_bf16(kf[1], qf[1], st, 0, 0, 0);
      #pragma unroll
      for (int i = 0; i < 4; ++i) {
        int kvi = kvb + 4*g + i;
        s8[sub*4 + i] = (kvi <= q0 + lo) ? st[i] : -1e30f;
      }
    }
    float tmax = s8[0];
    #pragma unroll
    for (int j = 1; j < 8; ++j) tmax = fmaxf(tmax, s8[j]);
    tmax = fmaxf(tmax, __shfl_xor(tmax, 16));
    tmax = fmaxf(tmax, __shfl_xor(tmax, 32));
    if (!__all(tmax <= m)) {
      float newm = fmaxf(m, tmax);
      float resc = __expf(m - newm);
      lsum *= resc;
      m = newm;
      #pragma unroll
      for (int i = 0; i < 4; ++i) {
        float rs = __shfl(resc, 4*g + i);
        of[0][i] *= rs; of[1][i] *= rs; of[2][i] *= rs; of[3][i] *= rs;
      }
    }
    float p8[8]; float psum = 0.f;
    #pragma unroll
    for (int j = 0; j < 8; ++j) { p8[j] = __expf(s8[j] - m); psum += p8[j]; }
    psum += __shfl_xor(psum, 16);
    psum += __shfl_xor(psum, 32);
    lsum += psum;
    unsigned int q4[4];
    #pragma unroll
    for (int c = 0; c < 4; ++c)
      asm("v_cvt_pk_bf16_f32 %0, %1, %2" : "=v"(q4[c]) : "v"(p8[2*c]), "v"(p8[2*c+1]));
    union { unsigned int wv[4]; bf16x8 v; } pu;
    #pragma unroll
    for (int j = 0; j < 4; ++j) {
      int srcLane = lo + lg2 + ((j >> 1) << 4);
      unsigned int lo_w = (unsigned int)__shfl((int)q4[j & 1], srcLane);
      unsigned int hi_w = (unsigned int)__shfl((int)q4[2 + (j & 1)], srcLane);
      pu.wv[j] = ghi ? hi_w : lo_w;
    }
    #pragma unroll
    for (int ch = 0; ch < 4; ++ch)
      of[ch] = __builtin_amdgcn_mfma_f32_16x16x32_bf16(pu.v, vf[ch], of[ch], 0, 0, 0);
  }

  #pragma unroll
  for (int i = 0; i < 4; ++i) {
    float li = 1.f / __shfl(lsum, 4*g + i);
    of[0][i] *= li; of[1][i] *= li; of[2][i] *= li; of[3][i] *= li;
  }
  ushort_t* yb = y + ((size_t)b*Tn + q0) * Cn + h*64;
  #pragma unroll
  for (int ch = 0; ch < 4; ++ch)
    #pragma unroll
    for (int i = 0; i < 4; ++i)
      yb[(size_t)(4*g + i) * Cn + ch*16 + lo] = f2bf(of[ch][i]);
}

// ---------------- launch ----------------
extern "C" void kernel_launch(void* const* d_in, const int* in_sizes, int n_in,
                              void* d_out, int out_size, void* d_ws, size_t ws_size,
                              hipStream_t stream) {
  const int*   idx     = (const int*)d_in[0];
  const float* tok_emb = (const float*)d_in[1];
  const float* pos_emb = (const float*)d_in[2];
  const float* ln1_g   = (const float*)d_in[3];
  const float* ln1_b   = (const float*)d_in[4];
  const float* qkv_w   = (const float*)d_in[5];
  const float* qkv_b   = (const float*)d_in[6];
  const float* aproj_w = (const float*)d_in[7];
  const float* aproj_b = (const float*)d_in[8];
  const float* ln2_g   = (const float*)d_in[9];
  const float* ln2_b   = (const float*)d_in[10];
  const float* fc_w    = (const float*)d_in[11];
  const float* fc_b    = (const float*)d_in[12];
  const float* mproj_w = (const float*)d_in[13];
  const float* mproj_b = (const float*)d_in[14];
  const float* lnf_g   = (const float*)d_in[15];
  const float* lnf_b   = (const float*)d_in[16];
  const float* head_w  = (const float*)d_in[17];
  float* out = (float*)d_out;

  char* ws = (char*)d_ws;
  float*    x    = (float*)(ws);                         // 12,582,912 B
  ushort_t* hA   = (ushort_t*)(ws + 12582912);           //  6,291,456 B
  ushort_t* hB   = (ushort_t*)(ws + 18874368);           // 25,165,824 B
  ushort_t* qkvh = (ushort_t*)(ws + 44040192);           // 25,165,824 B (q,k,vT,vtmp)
  ushort_t* wT   = (ushort_t*)(ws + 69206016);           // 77,463,552 B (layer pack / head Npad 50432)

  const int M = Bn * Tn;  // 4096
  dim3 tb(32, 8);

  embed_kernel<<<M, 192, 0, stream>>>(idx, tok_emb, pos_emb, x);
  for (int l = 0; l < Ln; ++l) {
    ln_kernel<<<M/4, 256, 0, stream>>>(x, ln1_g + l*Cn, ln1_b + l*Cn, hA);
    tcvt4_kernel<<<6912, tb, 0, stream>>>(qkv_w + (size_t)l*Cn*3*Cn, aproj_w + (size_t)l*Cn*Cn,
                                          fc_w + (size_t)l*Cn*4*Cn, mproj_w + (size_t)l*4*Cn*Cn, wT);
    gemm_kernel<3,128><<<dim3(M/128, 2304/128), 256, 0, stream>>>(hA, wT + OFF_QKV, qkv_b + (size_t)l*3*Cn, qkvh, nullptr, M, 2304, 768);
    vtrans_kernel<<<dim3(Tn/64, Bn*Hn), 256, 0, stream>>>(qkvh + 3*QKV_ELEMS, qkvh + 2*QKV_ELEMS);
    attn_kernel<<<dim3(128, Bn*Hn), 64, 0, stream>>>(qkvh, hA);
    gemm_kernel<1,64><<<dim3(M/64, 768/128), 256, 0, stream>>>(hA, wT + OFF_APROJ, aproj_b + (size_t)l*Cn, x, x, M, 768, 768);
    ln_kernel<<<M/4, 256, 0, stream>>>(x, ln2_g + l*Cn, ln2_b + l*Cn, hA);
    gemm_kernel<2,128><<<dim3(M/128, 3072/128), 256, 0, stream>>>(hA, wT + OFF_FC, fc_b + (size_t)l*4*Cn, hB, nullptr, M, 3072, 768);
    gemm_kernel<1,64><<<dim3(M/64, 768/128), 256, 0, stream>>>(hB, wT + OFF_MPROJ, mproj_b + (size_t)l*Cn, x, x, M, 768, 3072);
  }
  ln_kernel<<<M/4, 256, 0, stream>>>(x, lnf_g, lnf_b, hA);
  tcvt_kernel<<<dim3(50432/32, 768/32), tb, 0, stream>>>(head_w, wT, 768, Vn, 50432);
  gemm256_kernel<<<dim3(M/256, 50432/256), 512, 0, stream>>>(hA, wT, nullptr, out, M, Vn, 768);
}